// Round 1
// baseline (13932.809 us; speedup 1.0000x reference)
//
#include <hip/hip_runtime.h>
#include <cstddef>

#define BB 256   // batch
#define TT 4096  // time steps
#define HH 64    // hidden
#define G4 256   // 4*H gate rows

__device__ __forceinline__ float frcp(float x) { return __builtin_amdgcn_rcpf(x); }
__device__ __forceinline__ float fsigm(float x) { return frcp(1.f + __expf(-x)); }
__device__ __forceinline__ float ftanh(float x) {
    float ax = fabsf(x);
    float e  = __expf(-2.f * ax);          // in (0,1], never overflows
    float r  = (1.f - e) * frcp(1.f + e);
    return copysignf(r, x);
}

// One workgroup per batch element. 256 threads: thread t = 4*j + q owns gate
// row r = q*64 + j (PyTorch gate order i,f,g,o as q=0..3 blocks).
// Weights for the owned row live in registers; x_t / h_{t-1} in LDS (broadcast
// reads). One __syncthreads per time step. Layers >=1 run IN-PLACE on seq
// ([T][B][H] in d_ws): step t reads (t,b) then overwrites (t,b).
template <int IN, bool FIRST>
__global__ __launch_bounds__(256, 1)
void lstm_layer(const float* __restrict__ x0,   // FIRST: x [B][T][6]
                const float* __restrict__ Wih,  // [256][IN]
                const float* __restrict__ Whh,  // [256][64]
                const float* __restrict__ bih,  // [256]
                const float* __restrict__ bhh,  // [256]
                float* __restrict__ seq)        // [T][B][64] (in for !FIRST, out always)
{
    const int b   = blockIdx.x;
    const int tid = threadIdx.x;
    const int j   = tid >> 2;
    const int q   = tid & 3;
    const int r   = (q << 6) + j;

    // recurrent weights: row r of Whh, 64 floats in registers
    float4 wh[16];
#pragma unroll
    for (int k = 0; k < 16; ++k)
        wh[k] = reinterpret_cast<const float4*>(Whh + r * 64)[k];

    float4 wi4[FIRST ? 1 : 16];
    float  wi6[FIRST ? 6 : 1];
    if (FIRST) {
#pragma unroll
        for (int k = 0; k < 6; ++k) wi6[k] = Wih[r * 6 + k];
    } else {
#pragma unroll
        for (int k = 0; k < 16; ++k)
            wi4[k] = reinterpret_cast<const float4*>(Wih + r * 64)[k];
    }
    const float bias = bih[r] + bhh[r];

    __shared__ __align__(16) float hbuf[2][HH];
    __shared__ __align__(16) float xbuf[4][FIRST ? 8 : HH];

    if (tid < HH) hbuf[0][tid] = 0.f;
    // preload x for t = 0, 1 (prefetch depth 2)
    if (FIRST) {
        if (tid < 6) {
            xbuf[0][tid] = x0[((size_t)b * TT + 0) * 6 + tid];
            xbuf[1][tid] = x0[((size_t)b * TT + 1) * 6 + tid];
        }
    } else {
        if (tid < HH) {
            xbuf[0][tid] = seq[(0 * BB + b) * HH + tid];
            xbuf[1][tid] = seq[(1 * BB + b) * HH + tid];
        }
    }
    float c = 0.f;
    __syncthreads();

    for (int t = 0; t < TT; ++t) {
        // issue prefetch for t+2 early (lands in regs; LDS write at end of step)
        float xn = 0.f;
        const bool pf = (FIRST ? (tid < 6) : (tid < HH)) && (t + 2 < TT);
        if (pf) {
            if (FIRST) xn = x0[((size_t)b * TT + (t + 2)) * 6 + tid];
            else       xn = seq[((t + 2) * BB + b) * HH + tid];
        }

        float a0 = 0.f, a1 = 0.f, a2 = 0.f, a3 = 0.f;
        const float4* h4 = reinterpret_cast<const float4*>(hbuf[t & 1]);
#pragma unroll
        for (int k = 0; k < 16; ++k) {
            float4 hv = h4[k];
            a0 = fmaf(wh[k].x, hv.x, a0);
            a1 = fmaf(wh[k].y, hv.y, a1);
            a2 = fmaf(wh[k].z, hv.z, a2);
            a3 = fmaf(wh[k].w, hv.w, a3);
        }
        if (FIRST) {
            const float* xs = xbuf[t & 3];
            a0 = fmaf(wi6[0], xs[0], a0);
            a1 = fmaf(wi6[1], xs[1], a1);
            a2 = fmaf(wi6[2], xs[2], a2);
            a3 = fmaf(wi6[3], xs[3], a3);
            a0 = fmaf(wi6[4], xs[4], a0);
            a1 = fmaf(wi6[5], xs[5], a1);
        } else {
            const float4* x4 = reinterpret_cast<const float4*>(xbuf[t & 3]);
#pragma unroll
            for (int k = 0; k < 16; ++k) {
                float4 xv = x4[k];
                a0 = fmaf(wi4[k].x, xv.x, a0);
                a1 = fmaf(wi4[k].y, xv.y, a1);
                a2 = fmaf(wi4[k].z, xv.z, a2);
                a3 = fmaf(wi4[k].w, xv.w, a3);
            }
        }
        const float g = ((a0 + a1) + (a2 + a3)) + bias;

        // intra-quad exchange: var[m] = g of lane (q^m); gate s = var[q^s]
        const float va = g;
        const float vb = __shfl_xor(g, 1);
        const float vc = __shfl_xor(g, 2);
        const float vd = __shfl_xor(vb, 2);

        const float gi = (q == 0) ? va : (q == 1) ? vb : (q == 2) ? vc : vd;
        const float gf = (q == 0) ? vb : (q == 1) ? va : (q == 2) ? vd : vc;
        const float gg = (q == 0) ? vc : (q == 1) ? vd : (q == 2) ? va : vb;
        const float go = (q == 0) ? vd : (q == 1) ? vc : (q == 2) ? vb : va;

        const float fi = fsigm(gi);
        const float ff = fsigm(gf);
        const float gt = ftanh(gg);
        const float fo = fsigm(go);
        c = fmaf(ff, c, fi * gt);              // all 4 quad lanes replicate c_j
        const float hn = fo * ftanh(c);

        if (q == 0) {
            hbuf[(t + 1) & 1][j] = hn;
            seq[(t * BB + b) * HH + j] = hn;   // output of this layer
        }
        if (pf) xbuf[(t + 2) & 3][tid] = xn;
        __syncthreads();
    }
}

// out[b] = fc_b + sum_j relu(h[T-1][b][j]) * fc_w[j]
__global__ __launch_bounds__(256)
void fc_kernel(const float* __restrict__ seq, const float* __restrict__ fcw,
               const float* __restrict__ fcb, float* __restrict__ out)
{
    __shared__ float w[HH];
    const int tid = threadIdx.x;
    if (tid < HH) w[tid] = fcw[tid];
    __syncthreads();
    const float* h = &seq[((TT - 1) * BB + tid) * HH];
    float s = fcb[0];
#pragma unroll
    for (int jj = 0; jj < HH; ++jj)
        s = fmaf(fmaxf(h[jj], 0.f), w[jj], s);
    out[tid] = s;
}

extern "C" void kernel_launch(void* const* d_in, const int* in_sizes, int n_in,
                              void* d_out, int out_size, void* d_ws, size_t ws_size,
                              hipStream_t stream) {
    const float* x    = (const float*)d_in[0];  // [B][T][6]
    const float* Wih0 = (const float*)d_in[1];  // [256][6]
    const float* WihR = (const float*)d_in[2];  // [3][256][64]
    const float* Whh  = (const float*)d_in[3];  // [4][256][64]
    const float* bih  = (const float*)d_in[4];  // [4][256]
    const float* bhh  = (const float*)d_in[5];  // [4][256]
    const float* fcw  = (const float*)d_in[6];  // [1][64]
    const float* fcb  = (const float*)d_in[7];  // [1]
    float* out = (float*)d_out;
    float* seq = (float*)d_ws;                  // [T][B][64] fp32 = 268 MB

    dim3 grid(BB), block(256);

    // layer 0: reads x, writes seq
    lstm_layer<6, true><<<grid, block, 0, stream>>>(x, Wih0, Whh, bih, bhh, seq);
    // layers 1..3: in-place on seq
    for (int l = 1; l < 4; ++l) {
        lstm_layer<64, false><<<grid, block, 0, stream>>>(
            nullptr,
            WihR + (size_t)(l - 1) * G4 * HH,
            Whh  + (size_t)l * G4 * HH,
            bih  + (size_t)l * G4,
            bhh  + (size_t)l * G4,
            seq);
    }
    fc_kernel<<<dim3(1), block, 0, stream>>>(seq, fcw, fcb, out);
}

// Round 2
// 7397.562 us; speedup vs baseline: 1.8834x; 1.8834x over previous
//
#include <hip/hip_runtime.h>
#include <cstddef>

#define BB 256   // batch
#define TT 4096  // time steps
#define HH 64    // hidden
#define NT 512   // threads per block: 64 units x 8 K-slices
#define CH 16    // x-chunk depth (steps)

// LDS layout (float offsets). xc offset by +8 mod 32 vs hb so h-reads and
// x-reads land on disjoint banks.
#define HB_OFF 0            // h double buffer [2][64]
#define XC_OFF 136          // x chunks (layers>=1) [2][16][64]
#define XF_OFF (136 + 2048) // x chunks (layer 0, padded) [2][16][16]
#define SMEMF  (136 + 2048 + 512)

__device__ __forceinline__ float dpp_xor1(float x) {  // lane ^= 1 (quad_perm)
    return __int_as_float(__builtin_amdgcn_mov_dpp(__float_as_int(x), 0xB1, 0xF, 0xF, true));
}
__device__ __forceinline__ float dpp_xor2(float x) {  // lane ^= 2 (quad_perm)
    return __int_as_float(__builtin_amdgcn_mov_dpp(__float_as_int(x), 0x4E, 0xF, 0xF, true));
}
__device__ __forceinline__ float swz_xor4(float x) {  // lane ^= 4 (ds_swizzle)
    return __int_as_float(__builtin_amdgcn_ds_swizzle(__float_as_int(x), 0x101F));
}
__device__ __forceinline__ float frcp(float x) { return __builtin_amdgcn_rcpf(x); }
__device__ __forceinline__ float fsigm(float x) { return frcp(1.f + __expf(-x)); }

__device__ __forceinline__ void fma4(float& acc, const float4 w, const float4 x) {
    acc = fmaf(w.x, x.x, acc);
    acc = fmaf(w.y, x.y, acc);
    acc = fmaf(w.z, x.z, acc);
    acc = fmaf(w.w, x.w, acc);
}

// One block per batch element, 512 threads. Thread (j = tid>>3, e = tid&7):
// computes partials of unit j's 4 gate rows (r = 64q + j) over K-slice e
// (e<4: h cols [16e,16e+16); e>=4: x cols [16(e-4), +16)). Reduce over e via
// 2 DPP stages + 1 ds_swizzle (reduce-scatter -> lane e holds gate q=e&3),
// one nonlinearity per lane, 3-DPP gather, per-lane replicated c/h update.
template <bool FIRST, bool LAST>
__global__ __launch_bounds__(NT, 2)
void lstm_layer(const float* __restrict__ xg,   // FIRST: x [B][T][6]
                const float* __restrict__ Wih,  // [256][6] or [256][64]
                const float* __restrict__ Whh,  // [256][64]
                const float* __restrict__ bih,  // [256]
                const float* __restrict__ bhh,  // [256]
                float* __restrict__ seq)        // [T][B][64]
{
    const int b   = blockIdx.x;
    const int tid = threadIdx.x;
    const int j   = tid >> 3;
    const int e   = tid & 7;
    const int q   = e & 3;
    const bool qb0 = (e & 1) != 0;
    const bool qb1 = (e & 2) != 0;

    __shared__ __align__(16) float smem[SMEMF];
    float* const hb = smem + HB_OFF;
    float* const xc = smem + XC_OFF;
    float* const xf = smem + XF_OFF;

    // ---- weights: 16 float4 = 64 floats, register-resident ----
    float4 w00 = make_float4(0,0,0,0), w01 = w00, w02 = w00, w03 = w00;
    float4 w10 = w00, w11 = w00, w12 = w00, w13 = w00;
    float4 w20 = w00, w21 = w00, w22 = w00, w23 = w00;
    float4 w30 = w00, w31 = w00, w32 = w00, w33 = w00;

    if (!FIRST || e < 4) {
        const float* Wp  = (e < 4) ? Whh : Wih;
        const int   col0 = (e & 3) * 16;
#define LDW(p) { const float4* rp = (const float4*)(Wp + ((p<<6)+j)*HH + col0); \
                 w##p##0 = rp[0]; w##p##1 = rp[1]; w##p##2 = rp[2]; w##p##3 = rp[3]; }
        LDW(0) LDW(1) LDW(2) LDW(3)
#undef LDW
    } else if (e == 4) {  // FIRST layer, x slice: 6-wide rows, zero-padded to 16
        const float* r0 = Wih + ((0<<6)+j)*6;
        const float* r1 = Wih + ((1<<6)+j)*6;
        const float* r2 = Wih + ((2<<6)+j)*6;
        const float* r3 = Wih + ((3<<6)+j)*6;
        w00 = make_float4(r0[0],r0[1],r0[2],r0[3]); w01.x = r0[4]; w01.y = r0[5];
        w10 = make_float4(r1[0],r1[1],r1[2],r1[3]); w11.x = r1[4]; w11.y = r1[5];
        w20 = make_float4(r2[0],r2[1],r2[2],r2[3]); w21.x = r2[4]; w21.y = r2[5];
        w30 = make_float4(r3[0],r3[1],r3[2],r3[3]); w31.x = r3[4]; w31.y = r3[5];
    }
    const float biasq = bih[(q << 6) + j] + bhh[(q << 6) + j];
    const float sg = (q == 2) ? 2.f : 1.f;   // tanh-gate via 2*sigm(2x)-1
    const float og = (q == 2) ? -1.f : 0.f;

    // ---- prologue: zero pads, init h, stage chunk 0 ----
    if (FIRST) {
        for (int i = tid; i < 2 * CH * 16; i += NT) xf[i] = 0.f;
    }
    if (tid < HH) hb[tid] = 0.f;
    __syncthreads();  // xf zeros before data writes

    if (!FIRST) {
        const int rowt = tid >> 5, ln = tid & 31;
        float2 v = ((const float2*)&seq[((size_t)rowt * BB + b) * HH])[ln];
        *((float2*)&xc[(0 * CH + rowt) * HH + ln * 2]) = v;
    } else if (tid < 24) {
        float4 v = ((const float4*)(xg + (size_t)b * TT * 6))[tid];
        float tmp[4] = {v.x, v.y, v.z, v.w};
#pragma unroll
        for (int m = 0; m < 4; ++m) {
            int idx = tid * 4 + m;
            xf[(0 * CH + idx / 6) * 16 + idx % 6] = tmp[m];
        }
    }
    float c = 0.f;
    float2 pf2 = make_float2(0.f, 0.f);
    float4 pf4 = make_float4(0.f, 0.f, 0.f, 0.f);
    __syncthreads();

    for (int t = 0; t < TT; ++t) {
        const int ph = t & (CH - 1);
        const int ck = t >> 4;

        // issue chunk (ck+1) prefetch at phase 0 (lands at phase 8)
        if (ph == 0) {
            if (!FIRST) {
                const int rowt = (ck + 1) * CH + (tid >> 5);
                pf2 = (rowt < TT)
                    ? ((const float2*)&seq[((size_t)rowt * BB + b) * HH])[tid & 31]
                    : make_float2(0.f, 0.f);
            } else if (tid < 24 && ck + 1 < TT / CH) {
                pf4 = ((const float4*)(xg + (size_t)b * TT * 6 + (size_t)(ck + 1) * 96))[tid];
            }
        }

        // ---- gate partials: 4 x ds_read_b128 + 64 FMA ----
        const float* vsrc;
        if (e < 4) vsrc = hb + (t & 1) * HH + e * 16;
        else vsrc = FIRST ? (xf + ((ck & 1) * CH + ph) * 16)
                          : (xc + (((ck & 1) * CH + ph) * HH) + (e & 3) * 16);
        const float4* vp = (const float4*)vsrc;
        const float4 vv0 = vp[0], vv1 = vp[1], vv2 = vp[2], vv3 = vp[3];

        float p0a = 0, p0b = 0, p1a = 0, p1b = 0, p2a = 0, p2b = 0, p3a = 0, p3b = 0;
        fma4(p0a, w00, vv0); fma4(p0b, w01, vv1); fma4(p0a, w02, vv2); fma4(p0b, w03, vv3);
        fma4(p1a, w10, vv0); fma4(p1b, w11, vv1); fma4(p1a, w12, vv2); fma4(p1b, w13, vv3);
        fma4(p2a, w20, vv0); fma4(p2b, w21, vv1); fma4(p2a, w22, vv2); fma4(p2b, w23, vv3);
        fma4(p3a, w30, vv0); fma4(p3b, w31, vv1); fma4(p3a, w32, vv2); fma4(p3b, w33, vv3);
        const float a0 = p0a + p0b, a1 = p1a + p1b, a2 = p2a + p2b, a3 = p3a + p3b;

        // ---- reduce-scatter over e: lane ends with gate q = e&3 ----
        const float s0 = dpp_xor1(a0), s1 = dpp_xor1(a1);
        const float s2 = dpp_xor1(a2), s3 = dpp_xor1(a3);
        const float k0 = qb0 ? (a1 + s1) : (a0 + s0);   // gate (e&1)
        const float k2 = qb0 ? (a3 + s3) : (a2 + s2);   // gate (e&1)+2
        const float u0 = dpp_xor2(k0), u2 = dpp_xor2(k2);
        float g = qb1 ? (k2 + u2) : (k0 + u0);          // gate q over quad
        g += swz_xor4(g);                               // + complementary K half
        g += biasq;

        // ---- one nonlinearity per lane ----
        const float act = fmaf(sg, fsigm(g * sg), og);

        // ---- gather acts, c/h update (replicated across the 8 lanes) ----
        const float v1 = dpp_xor1(act);   // act of gate q^1
        const float v2 = dpp_xor2(act);   // act of gate q^2
        const float v3 = dpp_xor2(v1);    // act of gate q^3
        const float P1 = qb0 ? (v1 * v3) : (act * v2);  // sigm(i)*tanh(g)
        const float A  = qb0 ? act : v1;
        const float Bx = qb0 ? v2 : v3;
        const float fv = qb1 ? Bx : A;    // sigm(f)
        const float ov = qb1 ? A : Bx;    // sigm(o)

        c = fmaf(fv, c, P1);
        const float tc = fmaf(2.f, fsigm(2.f * c), -1.f);  // tanh(c)
        const float hn = ov * tc;

        if (e == 0) {
            hb[((t + 1) & 1) * HH + j] = hn;
            if (!LAST || t == TT - 1)
                seq[((size_t)t * BB + b) * HH + j] = hn;
        }

        // land the prefetched chunk at phase 8 (read starts at phase 16)
        if (ph == 8) {
            if (!FIRST) {
                *((float2*)&xc[(((ck + 1) & 1) * CH + (tid >> 5)) * HH + (tid & 31) * 2]) = pf2;
            } else if (tid < 24) {
                float tmp[4] = {pf4.x, pf4.y, pf4.z, pf4.w};
#pragma unroll
                for (int m = 0; m < 4; ++m) {
                    int idx = tid * 4 + m;
                    xf[(((ck + 1) & 1) * CH + idx / 6) * 16 + idx % 6] = tmp[m];
                }
            }
        }
        __syncthreads();
    }
}

// out[b] = fc_b + sum_j relu(h[T-1][b][j]) * fc_w[j]
__global__ __launch_bounds__(256)
void fc_kernel(const float* __restrict__ seq, const float* __restrict__ fcw,
               const float* __restrict__ fcb, float* __restrict__ out)
{
    __shared__ float w[HH];
    const int tid = threadIdx.x;
    if (tid < HH) w[tid] = fcw[tid];
    __syncthreads();
    const float* h = &seq[((size_t)(TT - 1) * BB + tid) * HH];
    float s = fcb[0];
#pragma unroll
    for (int jj = 0; jj < HH; ++jj)
        s = fmaf(fmaxf(h[jj], 0.f), w[jj], s);
    out[tid] = s;
}

extern "C" void kernel_launch(void* const* d_in, const int* in_sizes, int n_in,
                              void* d_out, int out_size, void* d_ws, size_t ws_size,
                              hipStream_t stream) {
    const float* x    = (const float*)d_in[0];  // [B][T][6]
    const float* Wih0 = (const float*)d_in[1];  // [256][6]
    const float* WihR = (const float*)d_in[2];  // [3][256][64]
    const float* Whh  = (const float*)d_in[3];  // [4][256][64]
    const float* bih  = (const float*)d_in[4];  // [4][256]
    const float* bhh  = (const float*)d_in[5];  // [4][256]
    const float* fcw  = (const float*)d_in[6];  // [1][64]
    const float* fcb  = (const float*)d_in[7];  // [1]
    float* out = (float*)d_out;
    float* seq = (float*)d_ws;                  // [T][B][64] fp32 = 268 MB

    dim3 grid(BB), block(NT);

    lstm_layer<true, false><<<grid, block, 0, stream>>>(x, Wih0, Whh, bih, bhh, seq);
    lstm_layer<false, false><<<grid, block, 0, stream>>>(
        nullptr, WihR + 0 * 256 * HH, Whh + 1 * 256 * HH, bih + 1 * 256, bhh + 1 * 256, seq);
    lstm_layer<false, false><<<grid, block, 0, stream>>>(
        nullptr, WihR + 1 * (size_t)256 * HH, Whh + 2 * (size_t)256 * HH, bih + 2 * 256, bhh + 2 * 256, seq);
    lstm_layer<false, true><<<grid, block, 0, stream>>>(
        nullptr, WihR + 2 * (size_t)256 * HH, Whh + 3 * (size_t)256 * HH, bih + 3 * 256, bhh + 3 * 256, seq);

    fc_kernel<<<dim3(1), dim3(256), 0, stream>>>(seq, fcw, fcb, out);
}

// Round 3
// 6828.250 us; speedup vs baseline: 2.0405x; 1.0834x over previous
//
#include <hip/hip_runtime.h>
#include <cstddef>

#define BB 256   // batch
#define TT 4096  // time steps
#define HH 64    // hidden
#define NT 512   // threads: 64 units x 8 K-slices
#define CH 16    // chunk depth (steps)
#define NCH (TT / CH)

// smem float layout (bank-tuned):
//   [8, 2056)    xc: 2 bufs x 16 rows x 64 cols  (base ≡ 8 mod 32)
//   [2064, 3088) hist ring: 16 rows x 64         (base ≡ 16 mod 32)
// -> every ds_read_b128 hits each bank-quad exactly 2-way (free, m136).
#define XC0   8
#define HIST0 2064
#define SMEMF 3092

__device__ __forceinline__ float dpp_xor1(float x) {  // lane ^= 1 (quad_perm)
    return __int_as_float(__builtin_amdgcn_mov_dpp(__float_as_int(x), 0xB1, 0xF, 0xF, true));
}
__device__ __forceinline__ float dpp_xor2(float x) {  // lane ^= 2 (quad_perm)
    return __int_as_float(__builtin_amdgcn_mov_dpp(__float_as_int(x), 0x4E, 0xF, 0xF, true));
}
__device__ __forceinline__ float swz_xor4(float x) {  // lane ^= 4 (ds_swizzle)
    return __int_as_float(__builtin_amdgcn_ds_swizzle(__float_as_int(x), 0x101F));
}
__device__ __forceinline__ float frcp(float x) { return __builtin_amdgcn_rcpf(x); }
__device__ __forceinline__ float fsigm(float x) { return frcp(1.f + __expf(-x)); }

__device__ __forceinline__ void fma4(float& acc, const float4 w, const float4 x) {
    acc = fmaf(w.x, x.x, acc);
    acc = fmaf(w.y, x.y, acc);
    acc = fmaf(w.z, x.z, acc);
    acc = fmaf(w.w, x.w, acc);
}

// One block per batch element, 512 threads. Thread (j = tid>>3, e = tid&7):
// partials of unit j's 4 gate rows over K-slice e (e<4: h cols [16e,+16);
// e>=4: x cols [16(e-4),+16)). Reduce via 2 DPP + 1 ds_swizzle, one
// nonlinearity per lane, 3-DPP gather, replicated c/h update. Fully unrolled
// 16-step chunks: all LDS addressing is base_reg + static immediate.
template <bool FIRST, bool LAST>
__global__ __launch_bounds__(NT, 2)
void lstm_layer(const float* __restrict__ xg,   // FIRST: x [B][T][6]
                const float* __restrict__ Wih,  // [256][6] or [256][64]
                const float* __restrict__ Whh,  // [256][64]
                const float* __restrict__ bih,  // [256]
                const float* __restrict__ bhh,  // [256]
                float* __restrict__ seq)        // [T][B][64]
{
    const int b   = blockIdx.x;
    const int tid = threadIdx.x;
    const int j   = tid >> 3;
    const int e   = tid & 7;
    const int eq  = e & 3;
    const int kb  = e >> 2;
    const bool qb0 = (e & 1) != 0;
    const bool qb1 = (e & 2) != 0;

    __shared__ __align__(16) float smem[SMEMF];

    // ---- weights: 16 float4 = 64 floats, register-resident ----
    float4 w[4][4];
#pragma unroll
    for (int q = 0; q < 4; ++q)
#pragma unroll
        for (int m = 0; m < 4; ++m) w[q][m] = make_float4(0.f, 0.f, 0.f, 0.f);

    if (!FIRST || kb == 0) {
        const float* Wp = kb ? Wih : Whh;
#pragma unroll
        for (int q = 0; q < 4; ++q) {
            const float4* rp = (const float4*)(Wp + ((q << 6) + j) * HH + eq * 16);
#pragma unroll
            for (int m = 0; m < 4; ++m) w[q][m] = rp[m];
        }
    } else if (e == 4) {  // FIRST, x-slice lane: 6-wide rows zero-padded
#pragma unroll
        for (int q = 0; q < 4; ++q) {
            const float* rp = Wih + ((q << 6) + j) * 6;
            w[q][0] = make_float4(rp[0], rp[1], rp[2], rp[3]);
            w[q][1].x = rp[4]; w[q][1].y = rp[5];
        }
    }
    const int rr = (eq << 6) + j;
    const float biasq = bih[rr] + bhh[rr];
    const float sg = (eq == 2) ? 2.f : 1.f;   // tanh gate via 2*sigm(2x)-1
    const float og = (eq == 2) ? -1.f : 0.f;

    // zero hist (h(-1)=0); FIRST also zeros xc (cols >=6 stay 0 forever)
    if (FIRST) { for (int i = tid; i < SMEMF; i += NT) smem[i] = 0.f; }
    else       { for (int i = HIST0 + tid; i < SMEMF; i += NT) smem[i] = 0.f; }
    __syncthreads();

    // ---- stage chunk 0 ----
    const int srow = tid >> 5;           // 0..15
    const int sc2  = (tid & 31) << 1;    // even col
    const float* gp = nullptr;
    const float* xp = nullptr;
    if (!FIRST) {
        gp = seq + ((size_t)srow * BB + b) * HH + sc2;
        float2 v = *(const float2*)gp;
        *(float2*)&smem[XC0 + srow * 64 + sc2] = v;
        gp += (size_t)CH * BB * HH;      // -> chunk 1
    } else {
        xp = xg + (size_t)b * TT * 6 + tid * 4;
        if (tid < 24) {
            float4 v = *(const float4*)xp;
            float tmp[4] = {v.x, v.y, v.z, v.w};
#pragma unroll
            for (int m = 0; m < 4; ++m) {
                int idx = tid * 4 + m;
                smem[XC0 + (idx / 6) * 64 + (idx % 6)] = tmp[m];
            }
        }
        xp += 96;
    }
    float* sp = seq + ((size_t)srow * BB + b) * HH + sc2;   // flush ptr
    float c = 0.f;
    __syncthreads();

    float2 pf2 = make_float2(0.f, 0.f);
    float4 pf4 = make_float4(0.f, 0.f, 0.f, 0.f);

    for (int ck = 0; ck < NCH; ++ck) {
        const int buf = ck & 1;
        // per-lane read bases: step ph reads vb + ph*64 (h: row ph-1; x: row ph);
        // ph==0 uses vb0 (h: row 15; x: row 0).
        const float* vb  = kb ? (smem + XC0 + buf * 1024 + eq * 16)
                              : (smem + HIST0 - 64 + eq * 16);
        const float* vb0 = kb ? vb : (smem + HIST0 + 15 * 64 + eq * 16);
        const bool pfv = (ck + 1 < NCH);

#pragma unroll
        for (int ph = 0; ph < CH; ++ph) {
            if (ph == 0 && pfv) {   // issue next-chunk global loads early
                if (!FIRST) pf2 = *(const float2*)gp;
                else if (tid < 24) pf4 = *(const float4*)xp;
            }

            const float4* vp = (const float4*)((ph == 0) ? vb0 : (vb + ph * 64));
            const float4 vv0 = vp[0], vv1 = vp[1], vv2 = vp[2], vv3 = vp[3];

            float a0, a1, a2, a3;
            {
                float pa, pb;
                pa = 0.f; pb = 0.f;
                fma4(pa, w[0][0], vv0); fma4(pb, w[0][1], vv1);
                fma4(pa, w[0][2], vv2); fma4(pb, w[0][3], vv3); a0 = pa + pb;
                pa = 0.f; pb = 0.f;
                fma4(pa, w[1][0], vv0); fma4(pb, w[1][1], vv1);
                fma4(pa, w[1][2], vv2); fma4(pb, w[1][3], vv3); a1 = pa + pb;
                pa = 0.f; pb = 0.f;
                fma4(pa, w[2][0], vv0); fma4(pb, w[2][1], vv1);
                fma4(pa, w[2][2], vv2); fma4(pb, w[2][3], vv3); a2 = pa + pb;
                pa = 0.f; pb = 0.f;
                fma4(pa, w[3][0], vv0); fma4(pb, w[3][1], vv1);
                fma4(pa, w[3][2], vv2); fma4(pb, w[3][3], vv3); a3 = pa + pb;
            }

            // reduce-scatter over e: lane ends with gate q = e&3
            const float s0 = dpp_xor1(a0), s1 = dpp_xor1(a1);
            const float s2 = dpp_xor1(a2), s3 = dpp_xor1(a3);
            const float k0 = qb0 ? (a1 + s1) : (a0 + s0);
            const float k2 = qb0 ? (a3 + s3) : (a2 + s2);
            const float u0 = dpp_xor2(k0), u2 = dpp_xor2(k2);
            float g = qb1 ? (k2 + u2) : (k0 + u0);
            g += swz_xor4(g);
            g += biasq;

            const float act = fmaf(sg, fsigm(g * sg), og);

            // gather acts, replicated c/h update
            const float v1 = dpp_xor1(act);
            const float v2 = dpp_xor2(act);
            const float v3 = dpp_xor2(v1);
            const float px = act * v2, py = v1 * v3;
            const float P1 = qb0 ? py : px;   // sigm(i)*tanh(g)
            const float A  = qb0 ? act : v1;
            const float Bx = qb0 ? v2 : v3;
            const float fv = qb1 ? Bx : A;    // sigm(f)
            const float ov = qb1 ? A : Bx;    // sigm(o)

            c = fmaf(fv, c, P1);
            const float tc = fmaf(2.f, fsigm(2.f * c), -1.f);  // tanh(c)
            const float hn = ov * tc;

            if (e == 0) smem[HIST0 + ph * 64 + j] = hn;   // hist[ph] = h(t)

            if (ph == 8 && pfv) {   // land next-chunk stage
                if (!FIRST) {
                    *(float2*)&smem[XC0 + (1 - buf) * 1024 + srow * 64 + sc2] = pf2;
                } else if (tid < 24) {
                    float tmp[4] = {pf4.x, pf4.y, pf4.z, pf4.w};
#pragma unroll
                    for (int m = 0; m < 4; ++m) {
                        int idx = tid * 4 + m;
                        smem[XC0 + (1 - buf) * 1024 + (idx / 6) * 64 + (idx % 6)] = tmp[m];
                    }
                }
            }
            __syncthreads();
        }

        // coalesced flush: hist rows 0..15 -> seq rows ck*16..+15
        if (!LAST) {
            float2 hv = *(const float2*)&smem[HIST0 + srow * 64 + sc2];
            *(float2*)sp = hv;
            __syncthreads();   // protect hist[0] from next chunk's ph0 write
        } else if (ck == NCH - 1) {
            if (srow == 15) {
                float2 hv = *(const float2*)&smem[HIST0 + 15 * 64 + sc2];
                *(float2*)sp = hv;
            }
        }
        sp += (size_t)CH * BB * HH;
        if (!FIRST) gp += (size_t)CH * BB * HH;
        else        xp += 96;
    }
}

// out[b] = fc_b + sum_j relu(h[T-1][b][j]) * fc_w[j]
__global__ __launch_bounds__(256)
void fc_kernel(const float* __restrict__ seq, const float* __restrict__ fcw,
               const float* __restrict__ fcb, float* __restrict__ out)
{
    __shared__ float w[HH];
    const int tid = threadIdx.x;
    if (tid < HH) w[tid] = fcw[tid];
    __syncthreads();
    const float* h = &seq[((size_t)(TT - 1) * BB + tid) * HH];
    float s = fcb[0];
#pragma unroll
    for (int jj = 0; jj < HH; ++jj)
        s = fmaf(fmaxf(h[jj], 0.f), w[jj], s);
    out[tid] = s;
}

extern "C" void kernel_launch(void* const* d_in, const int* in_sizes, int n_in,
                              void* d_out, int out_size, void* d_ws, size_t ws_size,
                              hipStream_t stream) {
    const float* x    = (const float*)d_in[0];  // [B][T][6]
    const float* Wih0 = (const float*)d_in[1];  // [256][6]
    const float* WihR = (const float*)d_in[2];  // [3][256][64]
    const float* Whh  = (const float*)d_in[3];  // [4][256][64]
    const float* bih  = (const float*)d_in[4];  // [4][256]
    const float* bhh  = (const float*)d_in[5];  // [4][256]
    const float* fcw  = (const float*)d_in[6];  // [1][64]
    const float* fcb  = (const float*)d_in[7];  // [1]
    float* out = (float*)d_out;
    float* seq = (float*)d_ws;                  // [T][B][64] fp32 = 268 MB

    dim3 grid(BB), block(NT);

    lstm_layer<true, false><<<grid, block, 0, stream>>>(x, Wih0, Whh, bih, bhh, seq);
    lstm_layer<false, false><<<grid, block, 0, stream>>>(
        nullptr, WihR + (size_t)0 * 256 * HH, Whh + (size_t)1 * 256 * HH,
        bih + 256, bhh + 256, seq);
    lstm_layer<false, false><<<grid, block, 0, stream>>>(
        nullptr, WihR + (size_t)1 * 256 * HH, Whh + (size_t)2 * 256 * HH,
        bih + 2 * 256, bhh + 2 * 256, seq);
    lstm_layer<false, true><<<grid, block, 0, stream>>>(
        nullptr, WihR + (size_t)2 * 256 * HH, Whh + (size_t)3 * 256 * HH,
        bih + 3 * 256, bhh + 3 * 256, seq);

    fc_kernel<<<dim3(1), dim3(256), 0, stream>>>(seq, fcw, fcb, out);
}